// Round 2
// baseline (142.885 us; speedup 1.0000x reference)
//
#include <hip/hip_runtime.h>

#define CELLS 49
#define CH 30
#define ROW (CELLS * CH)   // 1470 floats per batch element

__device__ __forceinline__ float waveReduce(float v) {
    #pragma unroll
    for (int o = 32; o > 0; o >>= 1) v += __shfl_xor(v, o, 64);
    return v;
}

__global__ __launch_bounds__(64) void yolo_main(const float* __restrict__ pred,
                                                const float* __restrict__ targ,
                                                float* __restrict__ ws, int B) {
    const int b = blockIdx.x;
    const int tid = threadIdx.x;

    __shared__ float sp[ROW];
    __shared__ float st[ROW];
    __shared__ int cellList[CELLS];
    __shared__ float bx1[2 * CELLS], by1[2 * CELLS], bx2[2 * CELLS], by2[2 * CELLS];

    // ---- coalesced global -> LDS staging (float2: row base is 8B-aligned) ----
    const float2* p2 = (const float2*)(pred + (size_t)b * ROW);
    const float2* t2 = (const float2*)(targ + (size_t)b * ROW);
    float2* sp2 = (float2*)sp;
    float2* st2 = (float2*)st;
    #pragma unroll
    for (int i = tid; i < ROW / 2; i += 64) {
        sp2[i] = p2[i];
        st2[i] = t2[i];
    }
    __syncthreads();

    float cls = 0.f, objc = 0.f, coord = 0.f;

    // ---- per-cell: noobj conf loss (folded x0.5) + class loss ----
    bool isObj = false;
    if (tid < CELLS) {
        const int base = tid * CH;
        const float ct = st[base + 4];
        isObj = ct > 0.f;
        if (!isObj) {
            float d4 = sp[base + 4] - ct;            // ct == 0
            float d9 = sp[base + 9] - st[base + 9];
            objc += 0.5f * (d4 * d4 + d9 * d9);      // NOOBJ_LAMBDA folded here
        } else {
            #pragma unroll
            for (int k = 10; k < CH; ++k) {
                float d = sp[base + k] - st[base + k];
                cls += d * d;
            }
        }
    }

    // ---- compact list of obj cells ----
    unsigned long long m = __ballot(isObj);
    int nObj = __popcll(m);
    if (isObj) {
        int pos = __popcll(m & ((1ull << tid) - 1ull));
        cellList[pos] = tid;
    }
    __syncthreads();

    const int nBox = 2 * nObj;

    // ---- precompute masked pred boxes' xyxy (compact) ----
    for (int e = tid; e < nBox; e += 64) {
        const int c = cellList[e >> 1];
        const int base = c * CH + (e & 1) * 5;
        float cx = sp[base], cy = sp[base + 1], w = sp[base + 2], h = sp[base + 3];
        bx1[e] = cx - 0.5f * w;
        by1[e] = cy - 0.5f * h;
        bx2[e] = cx + 0.5f * w;
        by2[e] = cy + 0.5f * h;
    }
    __syncthreads();

    // ---- per masked target box: max IoU over masked pred boxes; losses ----
    for (int e = tid; e < nBox; e += 64) {
        const int c = cellList[e >> 1];
        const int base = c * CH + (e & 1) * 5;
        const float tcx = st[base], tcy = st[base + 1];
        const float tw = st[base + 2], th = st[base + 3];
        const float tx1 = tcx - 0.5f * tw, ty1 = tcy - 0.5f * th;
        const float tx2 = tcx + 0.5f * tw, ty2 = tcy + 0.5f * th;
        const float ta = (tx2 - tx1) * (ty2 - ty1);

        float maxiou = 0.f;
        for (int i = 0; i < nBox; ++i) {
            float lx = fmaxf(bx1[i], tx1), ly = fmaxf(by1[i], ty1);
            float rx = fminf(bx2[i], tx2), ry = fminf(by2[i], ty2);
            float iw = fmaxf(rx - lx, 0.f), ih = fmaxf(ry - ly, 0.f);
            float inter = iw * ih;
            float pa = (bx2[i] - bx1[i]) * (by2[i] - by1[i]);
            float un = pa + ta - inter;
            float iou = inter / (un > 0.f ? un : 1.f);
            maxiou = fmaxf(maxiou, iou);
        }

        if (maxiou != 0.f) {                         // cmask
            float dcx = sp[base] - tcx;
            float dcy = sp[base + 1] - tcy;
            coord += dcx * dcx + dcy * dcy;
            float dw = sqrtf(sp[base + 2]) - sqrtf(tw);
            float dh = sqrtf(sp[base + 3]) - sqrtf(th);
            coord += dw * dw + dh * dh;
            float dc = sp[base + 4] - st[base + 4];
            objc += dc * dc;
        }
    }

    // ---- wave reduction + per-block partial write ----
    cls = waveReduce(cls);
    objc = waveReduce(objc);
    coord = waveReduce(coord);
    if (tid == 0) {
        ws[b] = cls;
        ws[B + b] = objc;
        ws[2 * B + b] = coord;
    }
}

__global__ __launch_bounds__(256) void yolo_reduce(const float* __restrict__ ws,
                                                   float* __restrict__ out, int B) {
    const int tid = threadIdx.x;
    float cls = 0.f, objc = 0.f, coord = 0.f;
    for (int i = tid; i < B; i += 256) {
        cls += ws[i];
        objc += ws[B + i];
        coord += ws[2 * B + i];
    }
    __shared__ float red[3][4];
    cls = waveReduce(cls);
    objc = waveReduce(objc);
    coord = waveReduce(coord);
    const int wave = tid >> 6;
    if ((tid & 63) == 0) {
        red[0][wave] = cls;
        red[1][wave] = objc;
        red[2][wave] = coord;
    }
    __syncthreads();
    if (tid == 0) {
        float c = red[0][0] + red[0][1] + red[0][2] + red[0][3];
        float o = red[1][0] + red[1][1] + red[1][2] + red[1][3];
        float x = red[2][0] + red[2][1] + red[2][2] + red[2][3];
        const float invB = 1.0f / (float)B;
        float bcls = c * invB;
        float bobj = o * invB;                 // noobj*0.5 already folded
        float bcoord = x * 5.0f * invB;        // COORD_LAMBDA
        out[0] = bcls + bobj + bcoord;
        out[1] = bcls;
        out[2] = bobj;
        out[3] = bcoord;
    }
}

extern "C" void kernel_launch(void* const* d_in, const int* in_sizes, int n_in,
                              void* d_out, int out_size, void* d_ws, size_t ws_size,
                              hipStream_t stream) {
    const float* pred = (const float*)d_in[0];
    const float* targ = (const float*)d_in[1];
    float* ws = (float*)d_ws;
    float* out = (float*)d_out;
    const int B = in_sizes[0] / ROW;

    yolo_main<<<B, 64, 0, stream>>>(pred, targ, ws, B);
    yolo_reduce<<<1, 256, 0, stream>>>(ws, out, B);
}

// Round 3
// 125.967 us; speedup vs baseline: 1.1343x; 1.1343x over previous
//
#include <hip/hip_runtime.h>

#define CH 30
#define CELLS 49
#define ROW (CELLS * CH)   // 1470 floats per batch row
#define RPB 4              // rows per block (one per wave)

__device__ __forceinline__ float waveReduce(float v) {
    #pragma unroll
    for (int o = 32; o > 0; o >>= 1) v += __shfl_xor(v, o, 64);
    return v;
}

__global__ __launch_bounds__(256) void yolo_main(const float* __restrict__ pred,
                                                 const float* __restrict__ targ,
                                                 float* __restrict__ ws,
                                                 int B, int NB) {
    const int w = threadIdx.x >> 6;
    const int lane = threadIdx.x & 63;
    const int r = blockIdx.x * RPB + w;

    __shared__ float4 boxS[RPB][98];   // pred boxes xyxy, read broadcast (no conflicts)
    __shared__ int clist[RPB][49];     // compacted obj-cell indices
    __shared__ float partial[RPB][3];

    const float* P = pred + (size_t)r * ROW;
    const float* T = targ + (size_t)r * ROW;
    const bool act = (lane < CELLS) && (r < B);

    float cls = 0.f, objc = 0.f, coord = 0.f;
    bool isObj = false;

    // ---- per-cell direct reads: conf/noobj for all cells, class for obj cells ----
    if (act) {
        const int cb = lane * CH;
        const float t4 = T[cb + 4];
        const float p4 = P[cb + 4];
        const float p9 = P[cb + 9];
        const float t9 = T[cb + 9];
        isObj = t4 > 0.f;
        if (!isObj) {
            const float d9 = p9 - t9;
            objc = 0.5f * (p4 * p4 + d9 * d9);   // NOOBJ_LAMBDA folded; t4 == 0
        } else {
            // class channels 10..29: byte offset cb*4+40 is 8-aligned -> float2
            const float2* pc = (const float2*)(P + cb + 10);
            const float2* tc = (const float2*)(T + cb + 10);
            #pragma unroll
            for (int k = 0; k < 10; ++k) {
                const float2 a = pc[k], b2 = tc[k];
                const float dx = a.x - b2.x, dy = a.y - b2.y;
                cls += dx * dx + dy * dy;
            }
        }
    }

    // ---- compact obj-cell list (order-preserving) ----
    const unsigned long long m = __ballot(isObj);
    const int nObj = __popcll(m);
    if (isObj) {
        const int pos = __popcll(m & ((1ull << lane) - 1ull));
        clist[w][pos] = lane;
    }
    __syncthreads();

    const int nBox = 2 * nObj;

    // ---- build masked pred boxes' xyxy ----
    for (int e = lane; e < nBox; e += 64) {
        const int c = clist[w][e >> 1];
        const float* pb = P + c * CH + (e & 1) * 5;
        const float cx = pb[0], cy = pb[1], bw = pb[2], bh = pb[3];
        boxS[w][e] = make_float4(cx - 0.5f * bw, cy - 0.5f * bh,
                                 cx + 0.5f * bw, cy + 0.5f * bh);
    }
    __syncthreads();

    // ---- per masked target box: max IoU over masked pred boxes; coord/obj losses ----
    for (int e = lane; e < nBox; e += 64) {
        const int c = clist[w][e >> 1];
        const int bb = c * CH + (e & 1) * 5;
        const float tcx = T[bb], tcy = T[bb + 1], tw = T[bb + 2], th = T[bb + 3];
        const float tx1 = tcx - 0.5f * tw, ty1 = tcy - 0.5f * th;
        const float tx2 = tcx + 0.5f * tw, ty2 = tcy + 0.5f * th;
        const float ta = (tx2 - tx1) * (ty2 - ty1);
        float maxiou = 0.f;
        for (int i = 0; i < nBox; ++i) {
            const float4 pb4 = boxS[w][i];          // broadcast read
            const float lx = fmaxf(pb4.x, tx1), ly = fmaxf(pb4.y, ty1);
            const float rx = fminf(pb4.z, tx2), ry = fminf(pb4.w, ty2);
            const float iw = fmaxf(rx - lx, 0.f), ih = fmaxf(ry - ly, 0.f);
            const float inter = iw * ih;
            const float pa = (pb4.z - pb4.x) * (pb4.w - pb4.y);
            const float un = pa + ta - inter;
            const float iou = inter / (un > 0.f ? un : 1.f);
            maxiou = fmaxf(maxiou, iou);
        }
        if (maxiou != 0.f) {                        // cmask
            const float dcx = P[bb] - tcx, dcy = P[bb + 1] - tcy;
            coord += dcx * dcx + dcy * dcy;
            const float dw = sqrtf(P[bb + 2]) - sqrtf(tw);
            const float dh = sqrtf(P[bb + 3]) - sqrtf(th);
            coord += dw * dw + dh * dh;
            const float dc = P[bb + 4] - T[bb + 4];
            objc += dc * dc;
        }
    }

    // ---- wave reduce, cross-wave via LDS, one partial triple per block ----
    cls = waveReduce(cls); objc = waveReduce(objc); coord = waveReduce(coord);
    if (lane == 0) { partial[w][0] = cls; partial[w][1] = objc; partial[w][2] = coord; }
    __syncthreads();
    if (threadIdx.x == 0) {
        float c = 0.f, o = 0.f, x = 0.f;
        #pragma unroll
        for (int i = 0; i < RPB; ++i) { c += partial[i][0]; o += partial[i][1]; x += partial[i][2]; }
        ws[blockIdx.x] = c;
        ws[NB + blockIdx.x] = o;
        ws[2 * NB + blockIdx.x] = x;
    }
}

__global__ __launch_bounds__(1024) void yolo_reduce(const float* __restrict__ ws,
                                                    float* __restrict__ out,
                                                    int NB, float invB) {
    const int tid = threadIdx.x;
    const int w = tid >> 6, lane = tid & 63;
    __shared__ float sred[16];
    __shared__ float sums[3];
    #pragma unroll
    for (int s = 0; s < 3; ++s) {
        float v = 0.f;
        for (int i = tid; i < NB; i += 1024) v += ws[s * NB + i];
        v = waveReduce(v);
        if (lane == 0) sred[w] = v;
        __syncthreads();
        if (tid == 0) {
            float t = 0.f;
            #pragma unroll
            for (int k = 0; k < 16; ++k) t += sred[k];
            sums[s] = t;
        }
        __syncthreads();
    }
    if (tid == 0) {
        const float bcls = sums[0] * invB;
        const float bobj = sums[1] * invB;          // noobj*0.5 folded upstream
        const float bcoord = sums[2] * 5.0f * invB; // COORD_LAMBDA
        out[0] = bcls + bobj + bcoord;
        out[1] = bcls;
        out[2] = bobj;
        out[3] = bcoord;
    }
}

extern "C" void kernel_launch(void* const* d_in, const int* in_sizes, int n_in,
                              void* d_out, int out_size, void* d_ws, size_t ws_size,
                              hipStream_t stream) {
    const float* pred = (const float*)d_in[0];
    const float* targ = (const float*)d_in[1];
    float* ws = (float*)d_ws;
    float* out = (float*)d_out;
    const int B = in_sizes[0] / ROW;
    const int NB = (B + RPB - 1) / RPB;

    yolo_main<<<NB, 256, 0, stream>>>(pred, targ, ws, B, NB);
    yolo_reduce<<<1, 1024, 0, stream>>>(ws, out, NB, 1.0f / (float)B);
}